// Round 3
// baseline (175.035 us; speedup 1.0000x reference)
//
#include <hip/hip_runtime.h>

#define N_NODES 100000
#define N_EDGES 2000000

typedef __bf16 bf16x8 __attribute__((ext_vector_type(8)));
typedef float f32x4 __attribute__((ext_vector_type(4)));
typedef float f32x16 __attribute__((ext_vector_type(16)));

__device__ __forceinline__ unsigned f2bf_rne(float f) {
  unsigned u = __builtin_bit_cast(unsigned, f);
  u += 0x7FFFu + ((u >> 16) & 1u);
  return u >> 16;
}

// Pack two NON-NEGATIVE f32 into bf16x2, round-half-up.
__device__ __forceinline__ unsigned pack_rhu(float lo, float hi) {
  unsigned ulo = __builtin_bit_cast(unsigned, lo) + 0x8000u;
  unsigned uhi = __builtin_bit_cast(unsigned, hi) + 0x8000u;
  return __builtin_amdgcn_perm(uhi, ulo, 0x07060302u);
}

// |a-b| on a packed bf16 pair -> packed bf16 pair.
__device__ __forceinline__ unsigned absdiff_pack(unsigned a, unsigned b) {
  float alo = __builtin_bit_cast(float, a << 16);
  float ahi = __builtin_bit_cast(float, a & 0xFFFF0000u);
  float blo = __builtin_bit_cast(float, b << 16);
  float bhi = __builtin_bit_cast(float, b & 0xFFFF0000u);
  return pack_rhu(fabsf(alo - blo), fabsf(ahi - bhi));
}

// ---------------------------------------------------------------------------
// Node MLP via MFMA, grid-stride (proven version, unchanged).
// ---------------------------------------------------------------------------
__global__ __launch_bounds__(64, 1) void node_mfma_kernel(
    const float* __restrict__ X, const float* __restrict__ W1,
    const float* __restrict__ b1, const float* __restrict__ W2,
    const float* __restrict__ b2, unsigned short* __restrict__ H) {
  const int lane = threadIdx.x;
  const int l15 = lane & 15;
  const int quad = lane >> 4;

  float w1v[2][4][8], b1v[2][8];
#pragma unroll
  for (int c = 0; c < 2; ++c)
#pragma unroll
    for (int j = 0; j < 8; ++j) {
      int col = c * 32 + quad * 8 + j;
      b1v[c][j] = b1[col];
#pragma unroll
      for (int d = 0; d < 4; ++d) w1v[c][d][j] = W1[d * 64 + col];
    }

  uint4 afr[2][4];
#pragma unroll
  for (int c = 0; c < 2; ++c)
#pragma unroll
    for (int mt = 0; mt < 4; ++mt) {
      unsigned w[4];
#pragma unroll
      for (int p = 0; p < 4; ++p) {
        int k = c * 32 + quad * 8 + 2 * p;
        unsigned lo = f2bf_rne(W2[k * 64 + mt * 16 + l15]);
        unsigned hi = f2bf_rne(W2[(k + 1) * 64 + mt * 16 + l15]);
        w[p] = lo | (hi << 16);
      }
      afr[c][mt] = make_uint4(w[0], w[1], w[2], w[3]);
    }
  float b2v[16];
#pragma unroll
  for (int mt = 0; mt < 4; ++mt)
#pragma unroll
    for (int r = 0; r < 4; ++r) b2v[mt * 4 + r] = b2[mt * 16 + quad * 4 + r];

  const int ntiles = N_NODES / 16;  // 6250
  for (int tile = blockIdx.x; tile < ntiles; tile += gridDim.x) {
    float4 xv = ((const float4*)X)[tile * 16 + l15];

    uint4 bfr[2];
#pragma unroll
    for (int c = 0; c < 2; ++c) {
      unsigned w[4];
#pragma unroll
      for (int p = 0; p < 4; ++p) {
        float h0 = fmaxf(b1v[c][2 * p] + xv.x * w1v[c][0][2 * p] +
                             xv.y * w1v[c][1][2 * p] + xv.z * w1v[c][2][2 * p] +
                             xv.w * w1v[c][3][2 * p],
                         0.f);
        float h1 = fmaxf(b1v[c][2 * p + 1] + xv.x * w1v[c][0][2 * p + 1] +
                             xv.y * w1v[c][1][2 * p + 1] +
                             xv.z * w1v[c][2][2 * p + 1] +
                             xv.w * w1v[c][3][2 * p + 1],
                         0.f);
        w[p] = pack_rhu(h0, h1);
      }
      bfr[c] = make_uint4(w[0], w[1], w[2], w[3]);
    }

    f32x4 acc[4];
#pragma unroll
    for (int mt = 0; mt < 4; ++mt) acc[mt] = (f32x4){0.f, 0.f, 0.f, 0.f};
#pragma unroll
    for (int c = 0; c < 2; ++c)
#pragma unroll
      for (int mt = 0; mt < 4; ++mt)
        acc[mt] = __builtin_amdgcn_mfma_f32_16x16x32_bf16(
            __builtin_bit_cast(bf16x8, afr[c][mt]),
            __builtin_bit_cast(bf16x8, bfr[c]), acc[mt], 0, 0, 0);

    unsigned short* hrow = H + (tile * 16 + l15) * 64;
#pragma unroll
    for (int mt = 0; mt < 4; ++mt) {
      unsigned lo = pack_rhu(fmaxf(acc[mt][0] + b2v[mt * 4 + 0], 0.f),
                             fmaxf(acc[mt][1] + b2v[mt * 4 + 1], 0.f));
      unsigned hi = pack_rhu(fmaxf(acc[mt][2] + b2v[mt * 4 + 2], 0.f),
                             fmaxf(acc[mt][3] + b2v[mt * 4 + 3], 0.f));
      *(uint2*)(hrow + mt * 16 + quad * 4) = make_uint2(lo, hi);
    }
  }
}

// ---------------------------------------------------------------------------
// Edge MLP v2: DIRECT-TO-VGPR gathers, no LDS.
//
// B-frag for mfma_32x32x16 chunk c is H[row][c*16+half*8 .. +7] — a
// contiguous 16B chunk — so global_load_dwordx4 delivers the fragment
// straight into the MFMA operand register. Identical L2 traffic to the old
// global_load_lds staging (same scattered 16B/lane pattern), but removes:
// 8 ds_read_b128 + addressing, the gather swizzle math, 2M bank-conflict
// cycles/dispatch, and the vmcnt(5) staging rigidity.
//
// Software pipeline in-register: after MFMA chunks c=0..7 consume hu/hv,
// issue next tile's 8 gathers into the SAME registers; the 10 remaining
// MFMAs (ab + bias) + epilogue + the next iteration's absdiff wait cover
// the L2/L3 gather latency. Peak pressure ~240 regs <= 256 at
// __launch_bounds__(256,2) -> same 2 waves/SIMD as before, no spill.
// ---------------------------------------------------------------------------
__global__ __launch_bounds__(256, 2) void edge_mlp_kernel(
    const unsigned short* __restrict__ H, const int* __restrict__ pairs,
    const float* __restrict__ We1, const float* __restrict__ be1,
    const float* __restrict__ We2, const float* __restrict__ be2,
    float* __restrict__ out) {
  const int tid = threadIdx.x;
  const int lane = tid & 63;
  const int n = lane & 31;     // edge within tile (MFMA col)
  const int half = lane >> 5;  // k-half
  const int wave = tid >> 6;

  // We1^T A-frags in registers: afr[c][mt] elem j =
  //   c<12 : We1[(c*16+half*8+j)*64 + mt*32+n]   (bf16 RNE packed)
  //   c==12: bias chunk A13[:,0]=be1 -> elem0 = be1[col] if half==0
  uint4 afr[13][2];
#pragma unroll
  for (int c = 0; c < 12; ++c)
#pragma unroll
    for (int mt = 0; mt < 2; ++mt) {
      int col = mt * 32 + n;
      int kb = c * 16 + half * 8;
      unsigned w[4];
#pragma unroll
      for (int p = 0; p < 4; ++p)
        w[p] = f2bf_rne(We1[(kb + 2 * p) * 64 + col]) |
               (f2bf_rne(We1[(kb + 2 * p + 1) * 64 + col]) << 16);
      afr[c][mt] = make_uint4(w[0], w[1], w[2], w[3]);
    }
#pragma unroll
  for (int mt = 0; mt < 2; ++mt)
    afr[12][mt] =
        make_uint4((half == 0) ? f2bf_rne(be1[mt * 32 + n]) : 0u, 0u, 0u, 0u);

  // B-frag for the bias chunk: B13[0][n]=1.0.
  const uint4 b13u = make_uint4((half == 0) ? 0x00003F80u : 0u, 0u, 0u, 0u);

  // We2 per-lane constants: row = mt*32 + (r&3)+8*(r>>2)+4*half.
  float we2v[32];
#pragma unroll
  for (int mt = 0; mt < 2; ++mt)
#pragma unroll
    for (int r = 0; r < 16; ++r)
      we2v[mt * 16 + r] = We2[mt * 32 + (r & 3) + 8 * (r >> 2) + 4 * half];
  const float be2v = be2[0];

  const int wid = blockIdx.x * 4 + wave;
  const int nw = gridDim.x * 4;  // 2048
  const int ntiles = N_EDGES / 32;
  const int last = ntiles - 1;
  const int2* pairs2 = (const int2*)pairs;

  // Fold this lane's k-half offset into the H base pointer: the chunk-c
  // fragment for row r is then ((uint4*)(Hh + r*64))[2*c].
  const unsigned short* Hh = H + half * 8;

  // Prologue: gathers for tile wid; pairs for tile wid+nw.
  int2 pr = pairs2[(size_t)wid * 32 + n];
  uint4 hu[4], hv[4];
  {
    const uint4* pu = (const uint4*)(Hh + (size_t)pr.x * 64);
    const uint4* pv = (const uint4*)(Hh + (size_t)pr.y * 64);
#pragma unroll
    for (int c = 0; c < 4; ++c) {
      hu[c] = pu[2 * c];
      hv[c] = pv[2 * c];
    }
  }
  {
    int t1 = wid + nw;
    if (t1 > last) t1 = last;  // clamped prefetch: idempotent, never stored
    pr = pairs2[(size_t)t1 * 32 + n];
  }

  for (int t = wid; t < ntiles; t += nw) {
    // hu/hv hold tile t's B-frags (loads in flight; compiler waits at use).
    uint4 ab[4];
#pragma unroll
    for (int c = 0; c < 4; ++c) {
      ab[c].x = absdiff_pack(hu[c].x, hv[c].x);
      ab[c].y = absdiff_pack(hu[c].y, hv[c].y);
      ab[c].z = absdiff_pack(hu[c].z, hv[c].z);
      ab[c].w = absdiff_pack(hu[c].w, hv[c].w);
    }

    f32x16 acc[2];
    acc[0] = (f32x16)(0.f);
    acc[1] = (f32x16)(0.f);

    // Chunks 0..3: hu. Chunks 4..7: hv. (These consume hu/hv.)
#pragma unroll
    for (int c = 0; c < 4; ++c) {
      bf16x8 b = __builtin_bit_cast(bf16x8, hu[c]);
#pragma unroll
      for (int mt = 0; mt < 2; ++mt)
        acc[mt] = __builtin_amdgcn_mfma_f32_32x32x16_bf16(
            __builtin_bit_cast(bf16x8, afr[c][mt]), b, acc[mt], 0, 0, 0);
    }
#pragma unroll
    for (int c = 0; c < 4; ++c) {
      bf16x8 b = __builtin_bit_cast(bf16x8, hv[c]);
#pragma unroll
      for (int mt = 0; mt < 2; ++mt)
        acc[mt] = __builtin_amdgcn_mfma_f32_32x32x16_bf16(
            __builtin_bit_cast(bf16x8, afr[4 + c][mt]), b, acc[mt], 0, 0, 0);
    }

    // hu/hv now dead: issue next tile's gathers into the same registers,
    // then refresh pr for the tile after. Latency hides under the ab+bias
    // MFMAs, the epilogue, and the next iteration's absdiff wait.
    {
      const uint4* pu = (const uint4*)(Hh + (size_t)pr.x * 64);
      const uint4* pv = (const uint4*)(Hh + (size_t)pr.y * 64);
#pragma unroll
      for (int c = 0; c < 4; ++c) {
        hu[c] = pu[2 * c];
        hv[c] = pv[2 * c];
      }
      int t2 = t + 2 * nw;
      if (t2 > last) t2 = last;
      pr = pairs2[(size_t)t2 * 32 + n];
    }
    __builtin_amdgcn_sched_barrier(0);  // pin gathers before trailing MFMAs

    // Chunks 8..11: |hu-hv|. Chunk 12: bias.
#pragma unroll
    for (int c = 0; c < 4; ++c) {
      bf16x8 b = __builtin_bit_cast(bf16x8, ab[c]);
#pragma unroll
      for (int mt = 0; mt < 2; ++mt)
        acc[mt] = __builtin_amdgcn_mfma_f32_32x32x16_bf16(
            __builtin_bit_cast(bf16x8, afr[8 + c][mt]), b, acc[mt], 0, 0, 0);
    }
#pragma unroll
    for (int mt = 0; mt < 2; ++mt)
      acc[mt] = __builtin_amdgcn_mfma_f32_32x32x16_bf16(
          __builtin_bit_cast(bf16x8, afr[12][mt]),
          __builtin_bit_cast(bf16x8, b13u), acc[mt], 0, 0, 0);

    float s = 0.f;
#pragma unroll
    for (int mt = 0; mt < 2; ++mt)
#pragma unroll
      for (int r = 0; r < 16; ++r)
        s += fmaxf(acc[mt][r], 0.f) * we2v[mt * 16 + r];
    s += __shfl_xor(s, 32);
    if (half == 0) out[t * 32 + n] = s + be2v;
  }
}

extern "C" void kernel_launch(void* const* d_in, const int* in_sizes, int n_in,
                              void* d_out, int out_size, void* d_ws,
                              size_t ws_size, hipStream_t stream) {
  const float* X = (const float*)d_in[0];
  const int* pairs = (const int*)d_in[1];
  const float* W1 = (const float*)d_in[2];
  const float* b1 = (const float*)d_in[3];
  const float* W2 = (const float*)d_in[4];
  const float* b2 = (const float*)d_in[5];
  const float* We1 = (const float*)d_in[6];
  const float* be1 = (const float*)d_in[7];
  const float* We2 = (const float*)d_in[8];
  const float* be2 = (const float*)d_in[9];
  float* out = (float*)d_out;
  unsigned short* H = (unsigned short*)d_ws;  // 100000*64 bf16 = 12.8 MB

  node_mfma_kernel<<<1024, 64, 0, stream>>>(X, W1, b1, W2, b2, H);
  // No LDS: occupancy is register-bound at 2 waves/SIMD -> 2 blocks/CU.
  // 512 blocks = exactly resident (persistent-style).
  edge_mlp_kernel<<<512, 256, 0, stream>>>(H, pairs, We1, be1, We2, be2, out);
}